// Round 6
// baseline (408.513 us; speedup 1.0000x reference)
//
#include <hip/hip_runtime.h>
#include <hip/hip_bf16.h>

typedef __attribute__((ext_vector_type(8))) short short8;
typedef __attribute__((ext_vector_type(4))) float float4_;

__device__ __forceinline__ void async16(const void* g, void* l) {
  __builtin_amdgcn_global_load_lds(
      (const __attribute__((address_space(1))) unsigned int*)g,
      (__attribute__((address_space(3))) unsigned int*)l, 16, 0, 0);
}

__device__ __forceinline__ short f2b(float f) {
  union { __hip_bfloat16 h; short s; } u;
  u.h = __float2bfloat16(f);
  return u.s;
}
__device__ __forceinline__ short8 cvt8(float4_ lo, float4_ hi) {
  short8 r;
#pragma unroll
  for (int t = 0; t < 4; t++) { r[t] = f2b(lo[t]); r[t + 4] = f2b(hi[t]); }
  return r;
}

// fp32 -> bf16 elementwise, n multiple of 8.
__global__ __launch_bounds__(256) void f32_to_b16(
    const float* __restrict__ in, short* __restrict__ out, long n)
{
  const long i = ((long)blockIdx.x * 256 + threadIdx.x) * 8;
  if (i >= n) return;
  float4_ lo = *(const float4_*)&in[i];
  float4_ hi = *(const float4_*)&in[i + 4];
  *(short8*)&out[i] = cvt8(lo, hi);
}

// out[C][R] = bf16(in[R][C])^T; in fp32. 64x64 LDS tiles (stride 72: 16B-aligned).
__global__ __launch_bounds__(256) void transpose64(
    const float* __restrict__ in, short* __restrict__ out, int R, int C)
{
  __shared__ __align__(16) short T[64 * 72];
  const int tid = threadIdx.x;
  const int r0 = blockIdx.y * 64;
  const int c0 = blockIdx.x * 64;
  const int r  = tid >> 2;
  const int cp = (tid & 3) * 16;
#pragma unroll
  for (int g = 0; g < 4; g++) {
    float4_ v = *(const float4_*)&in[(long)(r0 + r) * C + c0 + cp + g * 4];
#pragma unroll
    for (int t = 0; t < 4; t++) T[(cp + g * 4 + t) * 72 + r] = f2b(v[t]);
  }
  __syncthreads();
  const int c  = tid >> 2;
  const int rp = (tid & 3) * 16;
  short8 w0 = *(const short8*)&T[c * 72 + rp];
  short8 w1 = *(const short8*)&T[c * 72 + rp + 8];
  *(short8*)&out[(long)(c0 + c) * R + r0 + rp] = w0;
  *(short8*)&out[(long)(c0 + c) * R + r0 + rp + 8] = w1;
}

// C[M,N] = A[M,K] @ B[N,K]^T (+ bias). B bf16 (row stride K), async-staged.
// A bf16 async (a_f32=0) or fp32 plain-load+cvt (a_f32=1). C bf16, or fp32
// with fp32 bias when c_f32. 128x128 tile, 4 waves (2x2 of 64x64), BK=32.
__global__ __launch_bounds__(256) void gemm_bt(
    const void* __restrict__ Av, int lda, int a_f32,
    const short* __restrict__ B,
    void* __restrict__ Cv, int ldc, int c_f32,
    int K, const float* __restrict__ bias)
{
  __shared__ __align__(16) short As[128 * 32];
  __shared__ __align__(16) short Bs[128 * 32];
  const int tid  = threadIdx.x;
  const int lane = tid & 63;
  const int w    = tid >> 6;
  const int quad = lane >> 4;
  const int l15  = lane & 15;
  const int wm   = (w >> 1) * 64;
  const int wn   = (w & 1) * 64;
  const int m0   = blockIdx.y * 128;
  const int n0   = blockIdx.x * 128;

  float4_ acc[4][4] = {};

  const int srow = tid >> 2;        // 0..63
  const int kp   = (tid & 3) * 8;   // k-part (elements)
  char* AsW = (char*)As + w * 1024;  // wave-uniform LDS base; HW adds lane*16
  char* BsW = (char*)Bs + w * 1024;
  const short* Bb0 = B + (long)(n0 + srow) * K;
  const short* Bb1 = B + (long)(n0 + srow + 64) * K;

  for (int k0 = 0; k0 < K; k0 += 32) {
    // B: async global->LDS (issued first; drained by the barrier below)
    async16(Bb0 + k0 + kp, BsW);
    async16(Bb1 + k0 + kp, BsW + 4096);
    if (a_f32) {
      const float* Af = (const float*)Av;
      float4_ l0 = *(const float4_*)&Af[(long)(m0 + srow) * lda + k0 + kp];
      float4_ l1 = *(const float4_*)&Af[(long)(m0 + srow) * lda + k0 + kp + 4];
      float4_ h0 = *(const float4_*)&Af[(long)(m0 + srow + 64) * lda + k0 + kp];
      float4_ h1 = *(const float4_*)&Af[(long)(m0 + srow + 64) * lda + k0 + kp + 4];
      // prev-iter frag reads finished at the loop-end barrier, so LDS is free
      *(short8*)&As[srow * 32 + kp]        = cvt8(l0, l1);
      *(short8*)&As[(srow + 64) * 32 + kp] = cvt8(h0, h1);
    } else {
      const short* Ab = (const short*)Av;
      async16(Ab + (long)(m0 + srow) * lda + k0 + kp, AsW);
      async16(Ab + (long)(m0 + srow + 64) * lda + k0 + kp, AsW + 4096);
    }
    __syncthreads();  // drains vmcnt (async + loads) + lgkm; LDS tiles ready
    short8 a[4], b[4];
#pragma unroll
    for (int i = 0; i < 4; i++)
      a[i] = *(const short8*)&As[(wm + i * 16 + l15) * 32 + quad * 8];
#pragma unroll
    for (int j = 0; j < 4; j++)
      b[j] = *(const short8*)&Bs[(wn + j * 16 + l15) * 32 + quad * 8];
#pragma unroll
    for (int i = 0; i < 4; i++)
#pragma unroll
      for (int j = 0; j < 4; j++)
        acc[i][j] = __builtin_amdgcn_mfma_f32_16x16x32_bf16(a[i], b[j], acc[i][j], 0, 0, 0);
    __syncthreads();  // frag reads done before next iter's staging
  }

#pragma unroll
  for (int i = 0; i < 4; i++) {
    const int rm = m0 + wm + i * 16 + quad * 4;
#pragma unroll
    for (int j = 0; j < 4; j++) {
      const int cn = n0 + wn + j * 16 + l15;
      if (c_f32) {
        float* C = (float*)Cv;
        const float bv = bias ? bias[cn] : 0.0f;
#pragma unroll
        for (int r = 0; r < 4; r++)
          C[(long)(rm + r) * ldc + cn] = acc[i][j][r] + bv;
      } else {
        short* C = (short*)Cv;
#pragma unroll
        for (int r = 0; r < 4; r++)
          C[(long)(rm + r) * ldc + cn] = f2b(acc[i][j][r]);
      }
    }
  }
}

// Grid 256: block b -> diag block d=b>>1, 64-row half h=b&1.
// S = QK^T/32 for rows [d*128+h*64, +64) vs all 128 K-rows of the block;
// causal mask + softmax(+1e-6); P (bf16) written OVER the Q columns (Q of these
// rows is fully consumed in phase 1; rows are disjoint across blocks).
__global__ __launch_bounds__(256) void qk_softmax(short* __restrict__ qkv)
{
  __shared__ __align__(16) short Qs[64 * 32];
  __shared__ __align__(16) short Ks[128 * 32];
  const int tid  = threadIdx.x;
  const int lane = tid & 63;
  const int w    = tid >> 6;
  const int quad = lane >> 4;
  const int l15  = lane & 15;
  const int d    = blockIdx.x >> 1;
  const int h    = blockIdx.x & 1;
  const long rbase = (long)d * 128 * 3072;
  const short* Qg = qkv + rbase + (long)(h * 64) * 3072;
  const short* Kg = qkv + rbase + 1024;
  const int srow = tid >> 2;
  const int kp   = (tid & 3) * 8;

  float4_ acc[8] = {};
  for (int k0 = 0; k0 < 1024; k0 += 32) {
    async16(Qg + (long)srow * 3072 + k0 + kp, (char*)Qs + w * 1024);
    async16(Kg + (long)srow * 3072 + k0 + kp, (char*)Ks + w * 1024);
    async16(Kg + (long)(srow + 64) * 3072 + k0 + kp, (char*)Ks + 4096 + w * 1024);
    __syncthreads();
    short8 a = *(const short8*)&Qs[(w * 16 + l15) * 32 + quad * 8];
#pragma unroll
    for (int j = 0; j < 8; j++) {
      short8 b = *(const short8*)&Ks[(j * 16 + l15) * 32 + quad * 8];
      acc[j] = __builtin_amdgcn_mfma_f32_16x16x32_bf16(a, b, acc[j], 0, 0, 0);
    }
    __syncthreads();
  }

  const float scale = 0.03125f;  // 1024^-0.5
#pragma unroll
  for (int r = 0; r < 4; r++) {
    const int rloc = w * 16 + quad * 4 + r;  // 0..63 in this half
    const int rblk = h * 64 + rloc;          // 0..127 in the diag block
    float s[8];
    float mx = -3.0e38f;
#pragma unroll
    for (int j = 0; j < 8; j++) {
      const int col = j * 16 + l15;
      const float v = acc[j][r] * scale;
      s[j] = (col <= rblk) ? v : -3.0e38f;
      mx = fmaxf(mx, s[j]);
    }
    mx = fmaxf(mx, __shfl_xor(mx, 1));
    mx = fmaxf(mx, __shfl_xor(mx, 2));
    mx = fmaxf(mx, __shfl_xor(mx, 4));
    mx = fmaxf(mx, __shfl_xor(mx, 8));
    float p[8];
    float sum = 0.0f;
#pragma unroll
    for (int j = 0; j < 8; j++) {
      p[j] = (s[j] > -1.0e38f) ? __expf(s[j] - mx) : 0.0f;
      sum += p[j];
    }
    sum += __shfl_xor(sum, 1);
    sum += __shfl_xor(sum, 2);
    sum += __shfl_xor(sum, 4);
    sum += __shfl_xor(sum, 8);
    const float inv = 1.0f / (sum + 1e-6f);
#pragma unroll
    for (int j = 0; j < 8; j++)
      qkv[rbase + (long)rblk * 3072 + j * 16 + l15] = f2b(p[j] * inv);
  }
}

// Grid (8, 128): O[128, n0..n0+128) = P[128,128] @ V[128,1024] for diag block
// blockIdx.y. P read from Q cols; V strided from global; O written OVER the K
// columns (dead after qk_softmax; launch order gives device-wide ordering).
__global__ __launch_bounds__(256) void pv(short* __restrict__ qkv)
{
  __shared__ __align__(16) short Ps[128 * 136];  // row stride 136 (16B-aligned)
  const int tid  = threadIdx.x;
  const int lane = tid & 63;
  const int w    = tid >> 6;
  const int quad = lane >> 4;
  const int l15  = lane & 15;
  const long rbase = (long)blockIdx.y * 128 * 3072;
  const short* Pg = qkv + rbase;          // P in Q cols
  const short* Vg = qkv + rbase + 2048;   // V
  short* Og = qkv + rbase + 1024;         // O over K cols
  const int n0 = blockIdx.x * 128;

  // stage P[128][128] -> LDS (padded rows; plain loads, once per block)
  {
    const int pr = tid >> 2;
    const int pc = (tid & 3) * 32;
#pragma unroll
    for (int g = 0; g < 2; g++) {
      const int row = g * 64 + pr;
#pragma unroll
      for (int c = 0; c < 4; c++) {
        short8 v = *(const short8*)&Pg[(long)row * 3072 + pc + c * 8];
        *(short8*)&Ps[row * 136 + pc + c * 8] = v;
      }
    }
  }
  __syncthreads();

  for (int d0 = n0; d0 < n0 + 128; d0 += 64) {
    float4_ o[2][4] = {};
#pragma unroll
    for (int kk = 0; kk < 4; kk++) {
      short8 a0 = *(const short8*)&Ps[(w * 32 + l15) * 136 + kk * 32 + quad * 8];
      short8 a1 = *(const short8*)&Ps[(w * 32 + 16 + l15) * 136 + kk * 32 + quad * 8];
      const int kb = kk * 32 + quad * 8;
#pragma unroll
      for (int j = 0; j < 4; j++) {
        const int dd = d0 + j * 16 + l15;
        short8 b;
#pragma unroll
        for (int t = 0; t < 8; t++)
          b[t] = Vg[(long)(kb + t) * 3072 + dd];
        o[0][j] = __builtin_amdgcn_mfma_f32_16x16x32_bf16(a0, b, o[0][j], 0, 0, 0);
        o[1][j] = __builtin_amdgcn_mfma_f32_16x16x32_bf16(a1, b, o[1][j], 0, 0, 0);
      }
    }
#pragma unroll
    for (int i = 0; i < 2; i++)
#pragma unroll
      for (int j = 0; j < 4; j++)
#pragma unroll
        for (int r = 0; r < 4; r++) {
          const int rq = w * 32 + i * 16 + quad * 4 + r;
          const int dd = d0 + j * 16 + l15;
          Og[(long)rq * 3072 + dd] = f2b(o[i][j][r]);
        }
  }
}

extern "C" void kernel_launch(void* const* d_in, const int* in_sizes, int n_in,
                              void* d_out, int out_size, void* d_ws, size_t ws_size,
                              hipStream_t stream) {
  const float* x    = (const float*)d_in[0];  // [4,4096,1024] fp32
  const float* Wqkv = (const float*)d_in[1];  // [1024,3072]
  const float* Wout = (const float*)d_in[2];  // [1024,1024] (= [N][K] for @W_out^T)
  const float* bout = (const float*)d_in[3];  // [1024]
  float* out = (float*)d_out;                 // [4,4096,1024] fp32

  // ws layout (109.05 MB total -- the bound proven available by R5's full-width
  // write counters): region reuse via launch ordering: Q cols -> P; K cols -> O.
  char* ws = (char*)d_ws;
  short* WqkvT = (short*)ws;               // [3072][1024] bf16: 6,291,456 B
  short* Woutb = (short*)(ws + 6291456);   // [1024][1024] bf16: 2,097,152 B
  short* qkv   = (short*)(ws + 8388608);   // [16384][3072] bf16: 100,663,296 B

  transpose64<<<dim3(48, 16), 256, 0, stream>>>(Wqkv, WqkvT, 1024, 3072);
  f32_to_b16<<<512, 256, 0, stream>>>(Wout, Woutb, 1048576L);
  // qkv = x @ W_qkv  (A fp32 plain-staged, B bf16 async)
  gemm_bt<<<dim3(24, 128), 256, 0, stream>>>(x, 1024, 1, WqkvT,
                                             qkv, 3072, 0, 1024, nullptr);
  // P = softmax(mask(Q K^T / 32))  -> Q cols
  qk_softmax<<<256, 256, 0, stream>>>(qkv);
  // O = P V  -> K cols
  pv<<<dim3(8, 128), 256, 0, stream>>>(qkv);
  // out = O @ W_out^T + b_out  (A = K cols, fully async)
  gemm_bt<<<dim3(8, 128), 256, 0, stream>>>(qkv + 1024, 3072, 0, Woutb,
                                            out, 1024, 1, 1024, bout);
}